// Round 11
// baseline (334.458 us; speedup 1.0000x reference)
//
#include <hip/hip_runtime.h>
#include <hip/hip_bf16.h>
#include <math.h>

// N_IN=32, N_OUT=31, H=128, npts=65536.
// Per point: X_l (128x32) propagated through Z = W_l @ X, with
// X'[:, :31] = D * Z[:, :31], X'[:, 31] = tanh(Z[:,31] + b).
// MFMA 16x16x32 bf16. r10 base (512 thr, PB=4, L0 = MFMA on [I|x],
// direct scatter) with a 3-barrier pipelined schedule:
//   s = pass&1:  L0 -> XT[s]; L1: XT[s]->XT[1-s]; L2: XT[1-s]->XT[s];
//   L3(pass) runs in phase A of pass+1, reading XT[s(pass)] while
//   L0(pass+1) writes XT[s(pass+1)] (disjoint buffers, no barrier).
// Barriers/pass: A (post L3||L0), B (post L1), C (post L2 + xb publish).

using short8 = __attribute__((ext_vector_type(8))) short;
using f32x4  = __attribute__((ext_vector_type(4))) float;

#define PB 4          // points per pass
#define PPB 32        // points per block
#define NPASS (PPB / PB)
#define STRIDE 136    // ushort elems per XT row (272 B = 17*16: 16B-aligned rows)

__device__ __forceinline__ float fast_tanh(float z) {
    float e = __expf(2.0f * z);
    return 1.0f - 2.0f * __builtin_amdgcn_rcpf(e + 1.0f);
}

// pack 2 f32 -> 1 dword of 2 bf16 (v_cvt_pk_bf16_f32; no builtin on gfx950)
__device__ __forceinline__ unsigned pk2(float lo, float hi) {
    unsigned r;
    asm("v_cvt_pk_bf16_f32 %0, %1, %2" : "=v"(r) : "v"(lo), "v"(hi));
    return r;
}

__device__ __forceinline__ short8 pack8f(const float* s) {
    union { unsigned u[4]; short8 v; } r;
    #pragma unroll
    for (int qq = 0; qq < 4; ++qq) r.u[qq] = pk2(s[2 * qq], s[2 * qq + 1]);
    return r.v;
}

__device__ __forceinline__ short8 load_row8(const float* p) {
    float tmp[8];
    const float4* p4 = reinterpret_cast<const float4*>(p);
    float4 q0 = p4[0], q1 = p4[1];
    tmp[0]=q0.x; tmp[1]=q0.y; tmp[2]=q0.z; tmp[3]=q0.w;
    tmp[4]=q1.x; tmp[5]=q1.y; tmp[6]=q1.z; tmp[7]=q1.w;
    return pack8f(tmp);
}

__global__ void __launch_bounds__(512, 4)
node_mfma(const float* __restrict__ tptr,
          const float* __restrict__ y,
          const float* __restrict__ W0, const float* __restrict__ b0,
          const float* __restrict__ W1, const float* __restrict__ b1,
          const float* __restrict__ W2, const float* __restrict__ b2,
          const float* __restrict__ W3, const float* __restrict__ b3,
          float* __restrict__ out, float* __restrict__ jac, int npts) {
    __shared__ __align__(16) ushort XT[2][PB][32][STRIDE];
    __shared__ __align__(16) float xb[PB][32];

    const int tid  = threadIdx.x;
    const int w    = tid >> 6;
    const int lane = tid & 63;
    const int r16  = lane & 15;   // A-row / B-col / D-col within tile
    const int g    = lane >> 4;   // k-octet group; D rows = 4g..4g+3
    const int j    = 16 * w + r16;  // this wave's m-tile rows (layers 0-2)

    // ---- weights -> registers ----
    short8 aW0 = load_row8(W0 + j * 32 + g * 8);  // W0 A-frag (K=32)
    short8 aW[2][4];  // A-frags W1, W2
    #pragma unroll
    for (int kc = 0; kc < 4; ++kc) {
        aW[0][kc] = load_row8(W1 + j * 128 + kc * 32 + g * 8);
        aW[1][kc] = load_row8(W2 + j * 128 + kc * 32 + g * 8);
    }
    // layer 3 (padded to 32 rows): wave w -> (m=(w>>1)&1, n=w&1), pts (w>>2)+{0,2}
    const int mw = (w >> 1) & 1, nw = w & 1;
    const int r3 = 16 * mw + r16;
    short8 aW3[4];
    #pragma unroll
    for (int kc = 0; kc < 4; ++kc) {
        if (r3 < 31) aW3[kc] = load_row8(W3 + r3 * 128 + kc * 32 + g * 8);
        else { short8 z = {0,0,0,0,0,0,0,0}; aW3[kc] = z; }
    }

    // ---- one-hot B-frags for the identity columns of [I|x] ----
    short8 oh0, oh1;
    {
        union { ushort u[8]; short8 v; } z0, z1;
        #pragma unroll
        for (int i = 0; i < 8; ++i) {
            z0.u[i] = (g == (r16 >> 3) && i == (r16 & 7)) ? (ushort)0x3F80 : (ushort)0;
            z1.u[i] = (r16 < 15 && g == ((16 + r16) >> 3) && i == ((16 + r16) & 7))
                          ? (ushort)0x3F80 : (ushort)0;
        }
        oh0 = z0.v; oh1 = z1.v;
    }

    // ---- biases ----
    float bv0[4], bv[2][4], b3v[4];
    #pragma unroll
    for (int reg = 0; reg < 4; ++reg) {
        bv0[reg]   = b0[16 * w + 4 * g + reg];
        bv[0][reg] = b1[16 * w + 4 * g + reg];
        bv[1][reg] = b2[16 * w + 4 * g + reg];
        int o = 16 * mw + 4 * g + reg;
        b3v[reg] = (o < 31) ? b3[o] : 0.0f;
    }
    const float force = sinf(tptr[0]);

    // ---- shared epilogue: Z cols -> X' (D-scaled cols + tanh col) ----
    auto epi = [&](f32x4 a0, f32x4 a1, const float* bL4, ushort* dst) {
        float va[4], vb[4];
        #pragma unroll
        for (int reg = 0; reg < 4; ++reg) {
            float tv = fast_tanh(a1[reg] + bL4[reg]);
            float d  = 1.0f - tv * tv;
            float dd = __shfl(d, lane | 15, 64);
            va[reg] = dd * a0[reg];
            vb[reg] = (r16 == 15) ? tv : dd * a1[reg];
        }
        uint2 pa, pb;
        pa.x = pk2(va[0], va[1]); pa.y = pk2(va[2], va[3]);
        pb.x = pk2(vb[0], vb[1]); pb.y = pk2(vb[2], vb[3]);
        *reinterpret_cast<uint2*>(&dst[r16 * STRIDE + 16 * w + 4 * g])        = pa;
        *reinterpret_cast<uint2*>(&dst[(16 + r16) * STRIDE + 16 * w + 4 * g]) = pb;
    };

    // ---- layer 3 (pipelined one pass late): W3pad @ X2, direct scatter ----
    auto do_l3 = [&](int pb3, const ushort* bufb) {
        #pragma unroll
        for (int tsk = 0; tsk < 2; ++tsk) {
            const int pl = (w >> 2) + tsk * 2;
            f32x4 a = {0.f, 0.f, 0.f, 0.f};
            __builtin_amdgcn_s_setprio(1);
            #pragma unroll
            for (int kc = 0; kc < 4; ++kc) {
                short8 bf = *reinterpret_cast<const short8*>(
                    &bufb[(pl * 32 + 16 * nw + r16) * STRIDE + kc * 32 + g * 8]);
                a = __builtin_amdgcn_mfma_f32_16x16x32_bf16(aW3[kc], bf, a, 0, 0, 0);
            }
            __builtin_amdgcn_s_setprio(0);
            const size_t p = (size_t)(pb3 + pl);
            const int c = 16 * nw + r16;
            if ((int)p < npts) {
                #pragma unroll
                for (int reg = 0; reg < 4; ++reg) {
                    const int o = 16 * mw + 4 * g + reg;
                    if (o < 31) {
                        if (c == 31) out[p * 31 + o] = a[reg] + b3v[reg];
                        else         jac[(p * 31 + o) * 31 + c] = a[reg];
                    }
                }
            }
        }
    };

    // ---- y prefetch + publish xb for pass 0 ----
    const int pl0 = tid >> 5, c0 = tid & 31;
    const bool act = tid < PB * 32;
    float pf = 0.0f;
    if (act && c0 < 31) pf = y[(size_t)(blockIdx.x * PPB + pl0) * 31 + c0];
    if (act) xb[pl0][c0] = (c0 < 31) ? pf : force;
    __syncthreads();

    for (int pass = 0; pass < NPASS; ++pass) {
        const int s = pass & 1;
        const int pbase = blockIdx.x * PPB + pass * PB;

        // ======== phase A: L3(pass-1) reads XT[1-s]  ||  L0(pass) writes XT[s] ====
        // issue y prefetch for pass+1 early (consumed in phase C)
        if (act && c0 < 31 && pass + 1 < NPASS)
            pf = y[(size_t)(pbase + PB + pl0) * 31 + c0];

        if (pass > 0) do_l3(pbase - PB, &XT[1 - s][0][0][0]);

        #pragma unroll
        for (int pl = 0; pl < PB; ++pl) {
            float xa[8];
            const float4* xp = reinterpret_cast<const float4*>(&xb[pl][g * 8]);
            float4 x0 = xp[0], x1 = xp[1];
            xa[0]=x0.x; xa[1]=x0.y; xa[2]=x0.z; xa[3]=x0.w;
            xa[4]=x1.x; xa[5]=x1.y; xa[6]=x1.z; xa[7]=x1.w;
            short8 xpk = pack8f(xa);
            short8 bf1 = (r16 == 15) ? xpk : oh1;
            f32x4 a0 = {0.f,0.f,0.f,0.f}, a1 = {0.f,0.f,0.f,0.f};
            __builtin_amdgcn_s_setprio(1);
            a0 = __builtin_amdgcn_mfma_f32_16x16x32_bf16(aW0, oh0, a0, 0, 0, 0);
            a1 = __builtin_amdgcn_mfma_f32_16x16x32_bf16(aW0, bf1, a1, 0, 0, 0);
            __builtin_amdgcn_s_setprio(0);
            epi(a0, a1, bv0, &XT[s][pl][0][0]);
        }
        __syncthreads();  // [A]

        // ======== phase B: L1: XT[s] -> XT[1-s] ========
        #pragma unroll
        for (int pl = 0; pl < PB; ++pl) {
            f32x4 a0 = {0.f, 0.f, 0.f, 0.f}, a1 = {0.f, 0.f, 0.f, 0.f};
            __builtin_amdgcn_s_setprio(1);
            #pragma unroll
            for (int kc = 0; kc < 4; ++kc) {
                short8 bf0 = *reinterpret_cast<const short8*>(&XT[s][pl][r16][kc * 32 + g * 8]);
                short8 bf1 = *reinterpret_cast<const short8*>(&XT[s][pl][16 + r16][kc * 32 + g * 8]);
                a0 = __builtin_amdgcn_mfma_f32_16x16x32_bf16(aW[0][kc], bf0, a0, 0, 0, 0);
                a1 = __builtin_amdgcn_mfma_f32_16x16x32_bf16(aW[0][kc], bf1, a1, 0, 0, 0);
            }
            __builtin_amdgcn_s_setprio(0);
            epi(a0, a1, bv[0], &XT[1 - s][pl][0][0]);
        }
        __syncthreads();  // [B]

        // ======== phase C: L2: XT[1-s] -> XT[s]; publish xb(pass+1) ========
        #pragma unroll
        for (int pl = 0; pl < PB; ++pl) {
            f32x4 a0 = {0.f, 0.f, 0.f, 0.f}, a1 = {0.f, 0.f, 0.f, 0.f};
            __builtin_amdgcn_s_setprio(1);
            #pragma unroll
            for (int kc = 0; kc < 4; ++kc) {
                short8 bf0 = *reinterpret_cast<const short8*>(&XT[1 - s][pl][r16][kc * 32 + g * 8]);
                short8 bf1 = *reinterpret_cast<const short8*>(&XT[1 - s][pl][16 + r16][kc * 32 + g * 8]);
                a0 = __builtin_amdgcn_mfma_f32_16x16x32_bf16(aW[1][kc], bf0, a0, 0, 0, 0);
                a1 = __builtin_amdgcn_mfma_f32_16x16x32_bf16(aW[1][kc], bf1, a1, 0, 0, 0);
            }
            __builtin_amdgcn_s_setprio(0);
            epi(a0, a1, bv[1], &XT[s][pl][0][0]);
        }
        if (act && pass + 1 < NPASS) xb[pl0][c0] = (c0 < 31) ? pf : force;
        __syncthreads();  // [C]
    }

    // ---- epilogue: L3 for the final pass (X2 in XT[(NPASS-1)&1]) ----
    do_l3(blockIdx.x * PPB + (NPASS - 1) * PB, &XT[(NPASS - 1) & 1][0][0][0]);
}

extern "C" void kernel_launch(void* const* d_in, const int* in_sizes, int n_in,
                              void* d_out, int out_size, void* d_ws, size_t ws_size,
                              hipStream_t stream) {
    const float* t  = (const float*)d_in[0];
    const float* y  = (const float*)d_in[1];
    const float* W0 = (const float*)d_in[2];
    const float* b0 = (const float*)d_in[3];
    const float* W1 = (const float*)d_in[4];
    const float* b1 = (const float*)d_in[5];
    const float* W2 = (const float*)d_in[6];
    const float* b2 = (const float*)d_in[7];
    const float* W3 = (const float*)d_in[8];
    const float* b3 = (const float*)d_in[9];

    const int npts = in_sizes[1] / 31;  // 65536
    float* out = (float*)d_out;
    float* jac = out + (size_t)npts * 31;

    const int blocks = (npts + PPB - 1) / PPB;  // 2048
    node_mfma<<<blocks, 512, 0, stream>>>(t, y, W0, b0, W1, b1, W2, b2, W3, b3,
                                          out, jac, npts);
}